// Round 13
// baseline (308.898 us; speedup 1.0000x reference)
//
#include <hip/hip_runtime.h>
#include <hip/hip_bf16.h>
#include <math.h>

#define H 512
#define S 65
#define SP 80                // padded s-dimension (rows 65..79 zero/garbage)
#define HS (H * S)           // 33280
#define PHS (H * SP)         // 40960

// Buffers (ws):
//  y1:    [SP][H] embed output (pad rows zero).
//  kqvp:  layer1 KSPLIT=2: 18 arrays ((slot*3+which)*2+kidx)*PHS.
//         layers2/3 KSPLIT=4: 12 arrays ((which)*4+kidx)*PHS.
//  att1:  3 heads x PHS.
//  y2acc: lin1 accumulator (atomicAdd from mega_lin; relu inline in kqv2).
//  pacc2: lin2 segs 0..3 accumulator (atomicAdd from mega_lin).
//  y3:    layer-3 input, written complete+relu'd by attn2_lin2 (rows <65).
//  tacc:  [1024] lin3 accumulator (16 slices from mega_lin + 8 from attn3).
//  uacc:  [512] lin4 accumulator.

// ---------------------------------------------------------------------------
__global__ void scale_embed_zero_kernel(const float* __restrict__ inp,
                                        const float* __restrict__ emb,
                                        float* __restrict__ yT,
                                        float* __restrict__ y2acc,
                                        float* __restrict__ pacc2,
                                        float* __restrict__ tacc,
                                        float* __restrict__ uacc) {
    int i = blockIdx.x * 256 + threadIdx.x;
    if (i < PHS) {
        int s = i / H;
        int h = i % H;
        float v = 0.f;
        if (s < S) {
            float x = (s == 64) ? 1.0f : inp[s];
            v = emb[h * S + s] * x;
        }
        yT[i] = v;
        y2acc[i] = 0.f;
        pacc2[i] = 0.f;
    }
    if (blockIdx.x == 0) {
        int t = threadIdx.x;
        tacc[t] = 0.f; tacc[256 + t] = 0.f; tacc[512 + t] = 0.f; tacc[768 + t] = 0.f;
        uacc[t & 511] = 0.f;   // 256 threads cover 0..255
        uacc[256 + t] = 0.f;   // ...and 256..511 (t<256)
    }
}

// ---------------------------------------------------------------------------
__device__ __forceinline__ void mac4(float4& c, float ax, float ay, float az,
                                     float aw, const float4& w0, const float4& w1,
                                     const float4& w2, const float4& w3) {
    c.x = fmaf(ax, w0.x, c.x); c.y = fmaf(ax, w0.y, c.y);
    c.z = fmaf(ax, w0.z, c.z); c.w = fmaf(ax, w0.w, c.w);
    c.x = fmaf(ay, w1.x, c.x); c.y = fmaf(ay, w1.y, c.y);
    c.z = fmaf(ay, w1.z, c.z); c.w = fmaf(ay, w1.w, c.w);
    c.x = fmaf(az, w2.x, c.x); c.y = fmaf(az, w2.y, c.y);
    c.z = fmaf(az, w2.z, c.z); c.w = fmaf(az, w2.w, c.w);
    c.x = fmaf(aw, w3.x, c.x); c.y = fmaf(aw, w3.y, c.y);
    c.z = fmaf(aw, w3.z, c.z); c.w = fmaf(aw, w3.w, c.w);
}

// ---------------------------------------------------------------------------
// KQV GEMM, 32-wide n-tiles. C[s][n] = sum_k A[s][k]*W[n][k].
// RELU: apply fmax(.,0) to staged A (for the y2acc accumulator input).
// KSPLIT=2: grid.x=32 (K=256/block). KSPLIT=4: grid.x=64 (K=128/block).
// ---------------------------------------------------------------------------
template <int KSPLIT, int RELU>
__global__ void __launch_bounds__(256, 1)
kqv_gemm_tiled(const float* __restrict__ wq,
               const float* __restrict__ wk,
               const float* __restrict__ wv,
               int mat0,
               const float* __restrict__ src,
               float* __restrict__ part) {
    int slot  = blockIdx.z;
    int which = blockIdx.y;
    int mat = mat0 + slot;
    const float* W = (which == 0 ? wk : (which == 1 ? wq : wv)) + (size_t)mat * H * H;

    int n0   = (blockIdx.x & 15) * 32;
    int kidx = blockIdx.x >> 4;
    const int NCH = 8 / KSPLIT;

    __shared__ float Wt[64 * 32];
    __shared__ float As[SP * 68];

    int t  = threadIdx.x;
    int nq = t & 7;
    int g  = t >> 3;
    bool r2 = (g < 16);

    float4 acc0 = {0,0,0,0}, acc1 = {0,0,0,0}, acc2 = {0,0,0,0};

    for (int ch = 0; ch < NCH; ++ch) {
        int kc0 = (kidx * NCH + ch) * 64;
#pragma unroll
        for (int c = 0; c < 2; ++c) {
            int f = c * 256 + t;
            int wn  = f >> 4;
            int kf4 = f & 15;
            float4 w4 = *(const float4*)(W + (size_t)(n0 + wn) * H + kc0 + 4 * kf4);
            int sw = ((wn >> 2) ^ (kf4 & 7));
            int base = (4 * kf4) * 32 + 4 * sw + (wn & 3);
            Wt[base     ] = w4.x;
            Wt[base + 32] = w4.y;
            Wt[base + 64] = w4.z;
            Wt[base + 96] = w4.w;
        }
#pragma unroll
        for (int c = 0; c < 5; ++c) {
            int f = c * 256 + t;
            int as  = f >> 4;
            int kf4 = f & 15;
            float4 v = *(const float4*)(src + (size_t)as * H + kc0 + 4 * kf4);
            if (RELU) {
                v.x = fmaxf(v.x, 0.f); v.y = fmaxf(v.y, 0.f);
                v.z = fmaxf(v.z, 0.f); v.w = fmaxf(v.w, 0.f);
            }
            *(float4*)(&As[as * 68 + 4 * kf4]) = v;
        }
        __syncthreads();

#pragma unroll
        for (int k4 = 0; k4 < 16; ++k4) {
            int swc = 4 * (nq ^ (k4 & 7));
            float4 w0 = *(const float4*)(&Wt[(4 * k4 + 0) * 32 + swc]);
            float4 w1 = *(const float4*)(&Wt[(4 * k4 + 1) * 32 + swc]);
            float4 w2 = *(const float4*)(&Wt[(4 * k4 + 2) * 32 + swc]);
            float4 w3 = *(const float4*)(&Wt[(4 * k4 + 3) * 32 + swc]);
            {
                float4 a = *(const float4*)(&As[g * 68 + 4 * k4]);
                mac4(acc0, a.x, a.y, a.z, a.w, w0, w1, w2, w3);
            }
            {
                float4 a = *(const float4*)(&As[(g + 32) * 68 + 4 * k4]);
                mac4(acc1, a.x, a.y, a.z, a.w, w0, w1, w2, w3);
            }
            if (r2) {
                float4 a = *(const float4*)(&As[(g + 64) * 68 + 4 * k4]);
                mac4(acc2, a.x, a.y, a.z, a.w, w0, w1, w2, w3);
            }
        }
        __syncthreads();
    }

    float* P = part + (size_t)((slot * 3 + which) * KSPLIT + kidx) * PHS;
    *(float4*)(P + (size_t)g * H + n0 + 4 * nq) = acc0;
    *(float4*)(P + (size_t)(g + 32) * H + n0 + 4 * nq) = acc1;
    if (r2) *(float4*)(P + (size_t)(g + 64) * H + n0 + 4 * nq) = acc2;
}

// ---------------------------------------------------------------------------
// Score quarter t of dot(ka, q_b); NS = number of K-split partials of q.
// ---------------------------------------------------------------------------
template <int NS>
__device__ __forceinline__ float score_part(const float* __restrict__ Q,
                                            const float* __restrict__ ka,
                                            int b, int t) {
    const float4* q[NS];
#pragma unroll
    for (int n = 0; n < NS; ++n)
        q[n] = (const float4*)(Q + (size_t)n * PHS + (size_t)b * H) + t * 32;
    const float4* kl = (const float4*)ka + t * 32;
    float4 c0 = {0,0,0,0}, c1 = {0,0,0,0};
#pragma unroll
    for (int u = 0; u < 32; u += 2) {
        float4 qa = q[0][u], qc = q[0][u + 1];
#pragma unroll
        for (int n = 1; n < NS; ++n) {
            float4 qb = q[n][u], qd = q[n][u + 1];
            qa.x += qb.x; qa.y += qb.y; qa.z += qb.z; qa.w += qb.w;
            qc.x += qd.x; qc.y += qd.y; qc.z += qd.z; qc.w += qd.w;
        }
        float4 k0 = kl[u], k1 = kl[u + 1];
        c0.x = fmaf(k0.x, qa.x, c0.x);
        c0.y = fmaf(k0.y, qa.y, c0.y);
        c0.z = fmaf(k0.z, qa.z, c0.z);
        c0.w = fmaf(k0.w, qa.w, c0.w);
        c1.x = fmaf(k1.x, qc.x, c1.x);
        c1.y = fmaf(k1.y, qc.y, c1.y);
        c1.z = fmaf(k1.z, qc.z, c1.z);
        c1.w = fmaf(k1.w, qc.w, c1.w);
    }
    return ((c0.x + c0.y) + (c0.z + c0.w)) + ((c1.x + c1.y) + (c1.z + c1.w));
}

// ---------------------------------------------------------------------------
// Shared attention body: leaves softmax p[] and sums in LDS.
// ---------------------------------------------------------------------------
template <int NS>
__device__ __forceinline__ void attn_body(const float* __restrict__ K,
                                          const float* __restrict__ Q,
                                          int a, int tid,
                                          float* __restrict__ ka,
                                          float* __restrict__ sp,
                                          float* __restrict__ smv,
                                          float* __restrict__ p) {
    float k0 = 0.f, k1 = 0.f;
#pragma unroll
    for (int n = 0; n < NS; ++n) {
        k0 += K[(size_t)n * PHS + (size_t)a * H + tid];
        k1 += K[(size_t)n * PHS + (size_t)a * H + tid + 256];
    }
    ka[tid] = k0; ka[tid + 256] = k1;
    __syncthreads();

    {
        int b = tid & 63;
        int t = tid >> 6;
        sp[t * 65 + b] = score_part<NS>(Q, ka, b, t);
        if (tid < 4) sp[tid * 65 + 64] = score_part<NS>(Q, ka, 64, tid);
    }
    __syncthreads();

    if (tid < S) {
        smv[tid] = (sp[tid] + sp[65 + tid]) + (sp[130 + tid] + sp[195 + tid]);
    }
    __syncthreads();

    float maxv = -INFINITY;
    for (int i = 0; i < S; ++i) maxv = fmaxf(maxv, smv[i]);
    float sum = 0.0f;
    for (int i = 0; i < S; ++i) sum += expf(smv[i] - maxv);
    float inv = 1.0f / sum;
    if (tid < S) p[tid] = expf(smv[tid] - maxv) * inv;
    __syncthreads();
}

// ---------------------------------------------------------------------------
// Layer-1 attention: one block per (a, slot), NS=2, writes att rows.
// ---------------------------------------------------------------------------
__global__ void attn1_kernel(const float* __restrict__ kqvp,
                             float* __restrict__ att) {
    int a = blockIdx.x;
    int slot = blockIdx.y;
    int tid = threadIdx.x;

    const float* base = kqvp + (size_t)slot * 6 * PHS;
    const float* K = base;
    const float* Q = base + 2 * (size_t)PHS;
    const float* V = base + 4 * (size_t)PHS;
    float* ao = att + (size_t)slot * PHS + (size_t)a * H;

    __shared__ float ka[H];
    __shared__ float sp[4 * 65];
    __shared__ float smv[S];
    __shared__ float p[S];

    attn_body<2>(K, Q, a, tid, ka, sp, smv, p);

#pragma unroll
    for (int rep = 0; rep < 2; ++rep) {
        int hh = tid + rep * 256;
        float a0 = 0.f, a1 = 0.f;
#pragma unroll 4
        for (int b = 0; b < 64; b += 2) {
            float v0 = V[(size_t)(b    ) * H + hh] + V[PHS + (size_t)(b    ) * H + hh];
            float v1 = V[(size_t)(b + 1) * H + hh] + V[PHS + (size_t)(b + 1) * H + hh];
            a0 = fmaf(p[b    ], v0, a0);
            a1 = fmaf(p[b + 1], v1, a1);
        }
        a0 = fmaf(p[64], V[(size_t)64 * H + hh] + V[PHS + (size_t)64 * H + hh], a0);
        ao[hh] = a0 + a1;
    }
}

// ---------------------------------------------------------------------------
// 4-row linear block with atomicAdd output (accumulator pattern).
// ---------------------------------------------------------------------------
__device__ __forceinline__ void lin4row_atomic_dev(const float* __restrict__ att,
                                                   int col0,
                                                   const float* __restrict__ L,
                                                   float* __restrict__ dst,
                                                   int s0, int tid) {
    __shared__ float Ar[4 * 256];
    __shared__ float4 red[4 * 128];

    {
        int rr = tid >> 6;
        int cc = tid & 63;
        *(float4*)(&Ar[rr * 256 + cc * 4]) =
            *(const float4*)(att + (size_t)(s0 + rr) * H + col0 + cc * 4);
    }
    __syncthreads();

    int h4 = (tid & 127) * 4;
    int jh = tid >> 7;
    const float* Lj = L + (size_t)(jh * 128) * H + h4;
    const float* A0 = Ar + jh * 128;

    float4 c0 = {0,0,0,0}, c1 = {0,0,0,0}, c2 = {0,0,0,0}, c3 = {0,0,0,0};
#pragma unroll 8
    for (int j = 0; j < 128; ++j) {
        float4 L4 = *(const float4*)(Lj + (size_t)j * H);
        float a0 = A0[j], a1 = A0[256 + j], a2 = A0[512 + j], a3 = A0[768 + j];
        c0.x = fmaf(a0, L4.x, c0.x); c0.y = fmaf(a0, L4.y, c0.y);
        c0.z = fmaf(a0, L4.z, c0.z); c0.w = fmaf(a0, L4.w, c0.w);
        c1.x = fmaf(a1, L4.x, c1.x); c1.y = fmaf(a1, L4.y, c1.y);
        c1.z = fmaf(a1, L4.z, c1.z); c1.w = fmaf(a1, L4.w, c1.w);
        c2.x = fmaf(a2, L4.x, c2.x); c2.y = fmaf(a2, L4.y, c2.y);
        c2.z = fmaf(a2, L4.z, c2.z); c2.w = fmaf(a2, L4.w, c2.w);
        c3.x = fmaf(a3, L4.x, c3.x); c3.y = fmaf(a3, L4.y, c3.y);
        c3.z = fmaf(a3, L4.z, c3.z); c3.w = fmaf(a3, L4.w, c3.w);
    }

    if (jh == 1) {
        int x = tid & 127;
        red[x] = c0; red[128 + x] = c1; red[256 + x] = c2; red[384 + x] = c3;
    }
    __syncthreads();
    if (jh == 0) {
        float4 r0 = red[tid], r1 = red[128 + tid], r2 = red[256 + tid], r3 = red[384 + tid];
        c0.x += r0.x; c0.y += r0.y; c0.z += r0.z; c0.w += r0.w;
        c1.x += r1.x; c1.y += r1.y; c1.z += r1.z; c1.w += r1.w;
        c2.x += r2.x; c2.y += r2.y; c2.z += r2.z; c2.w += r2.w;
        c3.x += r3.x; c3.y += r3.y; c3.z += r3.z; c3.w += r3.w;
        float* d0 = dst + (size_t)(s0 + 0) * H + h4;
        float* d1 = dst + (size_t)(s0 + 1) * H + h4;
        float* d2 = dst + (size_t)(s0 + 2) * H + h4;
        float* d3 = dst + (size_t)(s0 + 3) * H + h4;
        atomicAdd(d0 + 0, c0.x); atomicAdd(d0 + 1, c0.y);
        atomicAdd(d0 + 2, c0.z); atomicAdd(d0 + 3, c0.w);
        atomicAdd(d1 + 0, c1.x); atomicAdd(d1 + 1, c1.y);
        atomicAdd(d1 + 2, c1.z); atomicAdd(d1 + 3, c1.w);
        atomicAdd(d2 + 0, c2.x); atomicAdd(d2 + 1, c2.y);
        atomicAdd(d2 + 2, c2.z); atomicAdd(d2 + 3, c2.w);
        atomicAdd(d3 + 0, c3.x); atomicAdd(d3 + 1, c3.y);
        atomicAdd(d3 + 2, c3.z); atomicAdd(d3 + 3, c3.w);
    }
}

// ---------------------------------------------------------------------------
// Mega linear: lin1 6 segs -> y2acc, lin2 segs 0..3 -> pacc2 (atomic),
// lin3 row-64 K-slices 0..15 -> tacc (atomic). Grid 234.
// ---------------------------------------------------------------------------
__global__ void mega_lin_kernel(const float* __restrict__ att1,
                                const float* __restrict__ lin1,
                                const float* __restrict__ lin2,
                                const float* __restrict__ lin3,
                                float* __restrict__ y2acc,
                                float* __restrict__ pacc2,
                                float* __restrict__ tacc) {
    int bx = blockIdx.x;
    int tid = threadIdx.x;

    if (bx < 170) {
        int seg = bx / 17;      // 0..9
        int pnum = bx % 17;
        const float* att;
        const float* L;
        float* dst;
        if (seg < 6) {
            att = att1 + (size_t)(seg >> 1) * PHS;
            L   = lin1 + (size_t)(seg * 256) * H;
            dst = y2acc;
        } else {
            int s2 = seg - 6;
            att = att1 + (size_t)(s2 >> 1) * PHS;
            L   = lin2 + (size_t)(s2 * 256) * H;
            dst = pacc2;
        }
        lin4row_atomic_dev(att, (seg & 1) * 256, L, dst, pnum * 4, tid);
    } else {
        int idx = bx - 170;                   // 0..63
        int j2 = (idx & 3) * 256 + tid;
        int ks = idx >> 2;                    // 0..15
        const float* row = att1 + (size_t)(ks >> 3) * PHS + (size_t)64 * H;
        int j0 = (ks & 7) * 64;
        int jbase = ks * 64;
        float a0 = 0.f, a1 = 0.f, a2 = 0.f, a3 = 0.f;
        for (int j = 0; j < 64; j += 4) {
            a0 = fmaf(row[j0 + j + 0], lin3[(size_t)(jbase + j + 0) * 1024 + j2], a0);
            a1 = fmaf(row[j0 + j + 1], lin3[(size_t)(jbase + j + 1) * 1024 + j2], a1);
            a2 = fmaf(row[j0 + j + 2], lin3[(size_t)(jbase + j + 2) * 1024 + j2], a2);
            a3 = fmaf(row[j0 + j + 3], lin3[(size_t)(jbase + j + 3) * 1024 + j2], a3);
        }
        atomicAdd(&tacc[j2], (a0 + a1) + (a2 + a3));
    }
}

// ---------------------------------------------------------------------------
// Fused layer-2 attention + lin2 segs 4,5 + pacc2 + relu -> y3 row a.
// 65 blocks, 256 thr, NS=4 kqvp layout (slot 0).
// ---------------------------------------------------------------------------
__global__ void attn2_lin2_kernel(const float* __restrict__ kqvp,
                                  const float* __restrict__ lin2,
                                  const float* __restrict__ pacc2,
                                  float* __restrict__ y3) {
    int a = blockIdx.x;
    int tid = threadIdx.x;

    const float* K = kqvp;
    const float* Q = kqvp + 4 * (size_t)PHS;
    const float* V = kqvp + 8 * (size_t)PHS;

    __shared__ float ka[H];
    __shared__ float sp[4 * 65];
    __shared__ float smv[S];
    __shared__ float p[S];
    __shared__ float arow[H];
    __shared__ float4 red[128];

    attn_body<4>(K, Q, a, tid, ka, sp, smv, p);

#pragma unroll
    for (int rep = 0; rep < 2; ++rep) {
        int hh = tid + rep * 256;
        float a0 = 0.f, a1 = 0.f;
#pragma unroll 4
        for (int b = 0; b < 64; b += 2) {
            float v0 = 0.f, v1 = 0.f;
#pragma unroll
            for (int n = 0; n < 4; ++n) {
                v0 += V[(size_t)n * PHS + (size_t)(b    ) * H + hh];
                v1 += V[(size_t)n * PHS + (size_t)(b + 1) * H + hh];
            }
            a0 = fmaf(p[b    ], v0, a0);
            a1 = fmaf(p[b + 1], v1, a1);
        }
        {
            float v0 = 0.f;
#pragma unroll
            for (int n = 0; n < 4; ++n) v0 += V[(size_t)n * PHS + (size_t)64 * H + hh];
            a0 = fmaf(p[64], v0, a0);
        }
        arow[hh] = a0 + a1;
    }
    __syncthreads();

    // lin2 rows 1024..1535: out[a][h] = sum_j arow[j]*lin2[(1024+j)*H+h]
    int h4 = (tid & 127) * 4;
    int jh = tid >> 7;
    const float* Lj = lin2 + (size_t)(1024 + jh * 256) * H + h4;
    const float* A0 = arow + jh * 256;

    float4 c = {0,0,0,0};
#pragma unroll 8
    for (int j = 0; j < 256; ++j) {
        float4 L4 = *(const float4*)(Lj + (size_t)j * H);
        float av = A0[j];
        c.x = fmaf(av, L4.x, c.x);
        c.y = fmaf(av, L4.y, c.y);
        c.z = fmaf(av, L4.z, c.z);
        c.w = fmaf(av, L4.w, c.w);
    }
    if (jh == 1) red[tid & 127] = c;
    __syncthreads();
    if (jh == 0) {
        float4 r = red[tid];
        float4 pa = *(const float4*)(pacc2 + (size_t)a * H + h4);
        c.x = fmaxf(c.x + r.x + pa.x, 0.f);
        c.y = fmaxf(c.y + r.y + pa.y, 0.f);
        c.z = fmaxf(c.z + r.z + pa.z, 0.f);
        c.w = fmaxf(c.w + r.w + pa.w, 0.f);
        *(float4*)(y3 + (size_t)a * H + h4) = c;
    }
}

// ---------------------------------------------------------------------------
// Layer-3 attention (row 64 only, NS=4) + lin3 slices 16..23 -> tacc (atomic).
// grid (4,8).
// ---------------------------------------------------------------------------
__global__ void attn3_lin3c_kernel(const float* __restrict__ kqvp,
                                   const float* __restrict__ lin3,
                                   float* __restrict__ tacc) {
    int tid = threadIdx.x;
    int ks  = 16 + blockIdx.y;
    int j2  = blockIdx.x * 256 + tid;
    int j0  = (ks & 7) * 64;

    const float* K = kqvp;
    const float* Q = kqvp + 4 * (size_t)PHS;
    const float* V = kqvp + 8 * (size_t)PHS;

    __shared__ float ka[H];
    __shared__ float sp[4 * 65];
    __shared__ float smv[S];
    __shared__ float p[S];
    __shared__ float att_s[64];

    attn_body<4>(K, Q, 64, tid, ka, sp, smv, p);

    if (tid < 64) {
        int hh = j0 + tid;
        float a0 = 0.f, a1 = 0.f;
#pragma unroll 4
        for (int b = 0; b < 64; b += 2) {
            float v0 = 0.f, v1 = 0.f;
#pragma unroll
            for (int n = 0; n < 4; ++n) {
                v0 += V[(size_t)n * PHS + (size_t)(b    ) * H + hh];
                v1 += V[(size_t)n * PHS + (size_t)(b + 1) * H + hh];
            }
            a0 = fmaf(p[b    ], v0, a0);
            a1 = fmaf(p[b + 1], v1, a1);
        }
        {
            float v0 = 0.f;
#pragma unroll
            for (int n = 0; n < 4; ++n) v0 += V[(size_t)n * PHS + (size_t)64 * H + hh];
            a0 = fmaf(p[64], v0, a0);
        }
        att_s[tid] = a0 + a1;
    }
    __syncthreads();

    int jbase = ks * 64;
    float a0 = 0.f, a1 = 0.f, a2 = 0.f, a3 = 0.f;
    for (int j = 0; j < 64; j += 4) {
        a0 = fmaf(att_s[j + 0], lin3[(size_t)(jbase + j + 0) * 1024 + j2], a0);
        a1 = fmaf(att_s[j + 1], lin3[(size_t)(jbase + j + 1) * 1024 + j2], a1);
        a2 = fmaf(att_s[j + 2], lin3[(size_t)(jbase + j + 2) * 1024 + j2], a2);
        a3 = fmaf(att_s[j + 3], lin3[(size_t)(jbase + j + 3) * 1024 + j2], a3);
    }
    atomicAdd(&tacc[j2], (a0 + a1) + (a2 + a3));
}

// ---------------------------------------------------------------------------
// lin4: t = relu(tacc); partial dot -> uacc (atomic). grid (2,16).
// ---------------------------------------------------------------------------
__global__ void lin4_kernel(const float* __restrict__ tacc,
                            const float* __restrict__ lin4,
                            float* __restrict__ uacc) {
    __shared__ float tl[64];
    int hh = blockIdx.x * 256 + threadIdx.x;
    int ks = blockIdx.y;
    int j2base = ks * 64;

    if (threadIdx.x < 64) {
        tl[threadIdx.x] = fmaxf(tacc[j2base + threadIdx.x], 0.f);
    }
    __syncthreads();

    float a0 = 0.f, a1 = 0.f, a2 = 0.f, a3 = 0.f;
    for (int j = 0; j < 64; j += 4) {
        a0 = fmaf(tl[j + 0], lin4[(size_t)(j2base + j + 0) * H + hh], a0);
        a1 = fmaf(tl[j + 1], lin4[(size_t)(j2base + j + 1) * H + hh], a1);
        a2 = fmaf(tl[j + 2], lin4[(size_t)(j2base + j + 2) * H + hh], a2);
        a3 = fmaf(tl[j + 3], lin4[(size_t)(j2base + j + 3) * H + hh], a3);
    }
    atomicAdd(&uacc[hh], (a0 + a1) + (a2 + a3));
}

__global__ void final_out_kernel(const float* __restrict__ uacc,
                                 const float* __restrict__ lin5,
                                 float* __restrict__ out) {
    __shared__ float u[H];
    __shared__ float pr[8][64];
    int tid = threadIdx.x;   // 512

    u[tid] = tanhf(uacc[tid]);
    __syncthreads();

    int o  = tid & 63;
    int sl = tid >> 6;
    float acc = 0.f;
    int h0 = sl * 64;
#pragma unroll 8
    for (int j = 0; j < 64; ++j) {
        acc = fmaf(u[h0 + j], lin5[(h0 + j) * 64 + o], acc);
    }
    pr[sl][o] = acc;
    __syncthreads();

    if (tid < 64) {
        float s = 0.f;
#pragma unroll
        for (int p = 0; p < 8; ++p) s += pr[p][tid];
        out[tid] = s;
    }
}

// ---------------------------------------------------------------------------
extern "C" void kernel_launch(void* const* d_in, const int* in_sizes, int n_in,
                              void* d_out, int out_size, void* d_ws, size_t ws_size,
                              hipStream_t stream) {
    const float* inputs  = (const float*)d_in[0];
    const float* emb     = (const float*)d_in[1];
    const float* wq      = (const float*)d_in[2];
    const float* wk      = (const float*)d_in[3];
    const float* wv      = (const float*)d_in[4];
    const float* linear1 = (const float*)d_in[5];
    const float* linear2 = (const float*)d_in[6];
    const float* linear3 = (const float*)d_in[7];
    const float* linear4 = (const float*)d_in[8];
    const float* linear5 = (const float*)d_in[9];
    float* out = (float*)d_out;

    float* ws    = (float*)d_ws;
    float* y1    = ws;                  // PHS
    float* kqvp  = y1    + PHS;         // 18*PHS max
    float* att1  = kqvp  + 18 * PHS;    // 3*PHS
    float* y2acc = att1  + 3 * PHS;     // PHS
    float* pacc2 = y2acc + PHS;         // PHS
    float* y3    = pacc2 + PHS;         // PHS
    float* tacc  = y3    + PHS;         // 1024
    float* uacc  = tacc  + 1024;        // 512

    const int nbp = PHS / 256;          // 160

    scale_embed_zero_kernel<<<nbp, 256, 0, stream>>>(inputs, emb, y1,
                                                     y2acc, pacc2, tacc, uacc);

    // ---- Layer 1 (KSPLIT=2: 288 blocks) ----
    kqv_gemm_tiled<2, 0><<<dim3(32, 3, 3), 256, 0, stream>>>(wq, wk, wv, 0, y1, kqvp);
    attn1_kernel<<<dim3(S, 3), 256, 0, stream>>>(kqvp, att1);
    mega_lin_kernel<<<234, 256, 0, stream>>>(att1, linear1, linear2, linear3,
                                             y2acc, pacc2, tacc);

    // ---- Layer 2 (head 2; KSPLIT=4: 192 blocks; relu inline on y2acc) ----
    kqv_gemm_tiled<4, 1><<<dim3(64, 3, 1), 256, 0, stream>>>(wq, wk, wv, 5, y2acc, kqvp);
    attn2_lin2_kernel<<<S, 256, 0, stream>>>(kqvp, linear2, pacc2, y3);

    // ---- Layer 3 (head 2; KSPLIT=4) ----
    kqv_gemm_tiled<4, 0><<<dim3(64, 3, 1), 256, 0, stream>>>(wq, wk, wv, 8, y3, kqvp);
    attn3_lin3c_kernel<<<dim3(4, 8), 256, 0, stream>>>(kqvp, linear3, tacc);

    // ---- Final ----
    lin4_kernel<<<dim3(2, 16), 256, 0, stream>>>(tacc, linear4, uacc);
    final_out_kernel<<<1, 512, 0, stream>>>(uacc, linear5, out);
}

// Round 14
// 280.315 us; speedup vs baseline: 1.1020x; 1.1020x over previous
//
#include <hip/hip_runtime.h>
#include <hip/hip_bf16.h>
#include <math.h>

#define H 512
#define S 65
#define SP 80                // padded s-dimension (rows 65..79 zero/garbage)
#define HS (H * S)           // 33280
#define PHS (H * SP)         // 40960

// Buffers (ws):
//  y1:    [SP][H] embed output (pad rows zero).
//  kqvp:  layer1 KSPLIT=2: 18 arrays ((slot*3+which)*2+kidx)*PHS.
//         layers2/3 KSPLIT=4: 12 arrays ((which)*4+kidx)*PHS.
//  att1:  3 heads x PHS.
//  y2acc: lin1 accumulator (atomicAdd from mega_lin; relu inline in kqv2).
//  pacc2: lin2 segs 0..3 accumulator (atomicAdd from mega_lin).
//  y3:    layer-3 input, written complete+relu'd by attn2_lin2 (rows <65).
//  tacc:  [1024] lin3 accumulator (16 slices from mega_lin + 8 from attn3).
//  uacc:  [512] lin4 accumulator.
//
// LESSON (rounds 4/8/13): every kernel with >~16 float4 accumulators/temps
// MUST carry __launch_bounds__(256,1) or the allocator caps VGPRs at the
// default-occupancy budget and spills to scratch (signature: VGPR=64 or 128
// exactly, WRITE_SIZE >> real output, dur 5-10x expected).

// ---------------------------------------------------------------------------
__global__ void scale_embed_zero_kernel(const float* __restrict__ inp,
                                        const float* __restrict__ emb,
                                        float* __restrict__ yT,
                                        float* __restrict__ y2acc,
                                        float* __restrict__ pacc2,
                                        float* __restrict__ tacc,
                                        float* __restrict__ uacc) {
    int i = blockIdx.x * 256 + threadIdx.x;
    if (i < PHS) {
        int s = i / H;
        int h = i % H;
        float v = 0.f;
        if (s < S) {
            float x = (s == 64) ? 1.0f : inp[s];
            v = emb[h * S + s] * x;
        }
        yT[i] = v;
        y2acc[i] = 0.f;
        pacc2[i] = 0.f;
    }
    if (blockIdx.x == 0) {
        int t = threadIdx.x;
        tacc[t] = 0.f; tacc[256 + t] = 0.f; tacc[512 + t] = 0.f; tacc[768 + t] = 0.f;
        uacc[t & 511] = 0.f;
        uacc[256 + t] = 0.f;
    }
}

// ---------------------------------------------------------------------------
__device__ __forceinline__ void mac4(float4& c, float ax, float ay, float az,
                                     float aw, const float4& w0, const float4& w1,
                                     const float4& w2, const float4& w3) {
    c.x = fmaf(ax, w0.x, c.x); c.y = fmaf(ax, w0.y, c.y);
    c.z = fmaf(ax, w0.z, c.z); c.w = fmaf(ax, w0.w, c.w);
    c.x = fmaf(ay, w1.x, c.x); c.y = fmaf(ay, w1.y, c.y);
    c.z = fmaf(ay, w1.z, c.z); c.w = fmaf(ay, w1.w, c.w);
    c.x = fmaf(az, w2.x, c.x); c.y = fmaf(az, w2.y, c.y);
    c.z = fmaf(az, w2.z, c.z); c.w = fmaf(az, w2.w, c.w);
    c.x = fmaf(aw, w3.x, c.x); c.y = fmaf(aw, w3.y, c.y);
    c.z = fmaf(aw, w3.z, c.z); c.w = fmaf(aw, w3.w, c.w);
}

// ---------------------------------------------------------------------------
// KQV GEMM, 32-wide n-tiles. C[s][n] = sum_k A[s][k]*W[n][k].
// ---------------------------------------------------------------------------
template <int KSPLIT, int RELU>
__global__ void __launch_bounds__(256, 1)
kqv_gemm_tiled(const float* __restrict__ wq,
               const float* __restrict__ wk,
               const float* __restrict__ wv,
               int mat0,
               const float* __restrict__ src,
               float* __restrict__ part) {
    int slot  = blockIdx.z;
    int which = blockIdx.y;
    int mat = mat0 + slot;
    const float* W = (which == 0 ? wk : (which == 1 ? wq : wv)) + (size_t)mat * H * H;

    int n0   = (blockIdx.x & 15) * 32;
    int kidx = blockIdx.x >> 4;
    const int NCH = 8 / KSPLIT;

    __shared__ float Wt[64 * 32];
    __shared__ float As[SP * 68];

    int t  = threadIdx.x;
    int nq = t & 7;
    int g  = t >> 3;
    bool r2 = (g < 16);

    float4 acc0 = {0,0,0,0}, acc1 = {0,0,0,0}, acc2 = {0,0,0,0};

    for (int ch = 0; ch < NCH; ++ch) {
        int kc0 = (kidx * NCH + ch) * 64;
#pragma unroll
        for (int c = 0; c < 2; ++c) {
            int f = c * 256 + t;
            int wn  = f >> 4;
            int kf4 = f & 15;
            float4 w4 = *(const float4*)(W + (size_t)(n0 + wn) * H + kc0 + 4 * kf4);
            int sw = ((wn >> 2) ^ (kf4 & 7));
            int base = (4 * kf4) * 32 + 4 * sw + (wn & 3);
            Wt[base     ] = w4.x;
            Wt[base + 32] = w4.y;
            Wt[base + 64] = w4.z;
            Wt[base + 96] = w4.w;
        }
#pragma unroll
        for (int c = 0; c < 5; ++c) {
            int f = c * 256 + t;
            int as  = f >> 4;
            int kf4 = f & 15;
            float4 v = *(const float4*)(src + (size_t)as * H + kc0 + 4 * kf4);
            if (RELU) {
                v.x = fmaxf(v.x, 0.f); v.y = fmaxf(v.y, 0.f);
                v.z = fmaxf(v.z, 0.f); v.w = fmaxf(v.w, 0.f);
            }
            *(float4*)(&As[as * 68 + 4 * kf4]) = v;
        }
        __syncthreads();

#pragma unroll
        for (int k4 = 0; k4 < 16; ++k4) {
            int swc = 4 * (nq ^ (k4 & 7));
            float4 w0 = *(const float4*)(&Wt[(4 * k4 + 0) * 32 + swc]);
            float4 w1 = *(const float4*)(&Wt[(4 * k4 + 1) * 32 + swc]);
            float4 w2 = *(const float4*)(&Wt[(4 * k4 + 2) * 32 + swc]);
            float4 w3 = *(const float4*)(&Wt[(4 * k4 + 3) * 32 + swc]);
            {
                float4 a = *(const float4*)(&As[g * 68 + 4 * k4]);
                mac4(acc0, a.x, a.y, a.z, a.w, w0, w1, w2, w3);
            }
            {
                float4 a = *(const float4*)(&As[(g + 32) * 68 + 4 * k4]);
                mac4(acc1, a.x, a.y, a.z, a.w, w0, w1, w2, w3);
            }
            if (r2) {
                float4 a = *(const float4*)(&As[(g + 64) * 68 + 4 * k4]);
                mac4(acc2, a.x, a.y, a.z, a.w, w0, w1, w2, w3);
            }
        }
        __syncthreads();
    }

    float* P = part + (size_t)((slot * 3 + which) * KSPLIT + kidx) * PHS;
    *(float4*)(P + (size_t)g * H + n0 + 4 * nq) = acc0;
    *(float4*)(P + (size_t)(g + 32) * H + n0 + 4 * nq) = acc1;
    if (r2) *(float4*)(P + (size_t)(g + 64) * H + n0 + 4 * nq) = acc2;
}

// ---------------------------------------------------------------------------
template <int NS>
__device__ __forceinline__ float score_part(const float* __restrict__ Q,
                                            const float* __restrict__ ka,
                                            int b, int t) {
    const float4* q[NS];
#pragma unroll
    for (int n = 0; n < NS; ++n)
        q[n] = (const float4*)(Q + (size_t)n * PHS + (size_t)b * H) + t * 32;
    const float4* kl = (const float4*)ka + t * 32;
    float4 c0 = {0,0,0,0}, c1 = {0,0,0,0};
#pragma unroll
    for (int u = 0; u < 32; u += 2) {
        float4 qa = q[0][u], qc = q[0][u + 1];
#pragma unroll
        for (int n = 1; n < NS; ++n) {
            float4 qb = q[n][u], qd = q[n][u + 1];
            qa.x += qb.x; qa.y += qb.y; qa.z += qb.z; qa.w += qb.w;
            qc.x += qd.x; qc.y += qd.y; qc.z += qd.z; qc.w += qd.w;
        }
        float4 k0 = kl[u], k1 = kl[u + 1];
        c0.x = fmaf(k0.x, qa.x, c0.x);
        c0.y = fmaf(k0.y, qa.y, c0.y);
        c0.z = fmaf(k0.z, qa.z, c0.z);
        c0.w = fmaf(k0.w, qa.w, c0.w);
        c1.x = fmaf(k1.x, qc.x, c1.x);
        c1.y = fmaf(k1.y, qc.y, c1.y);
        c1.z = fmaf(k1.z, qc.z, c1.z);
        c1.w = fmaf(k1.w, qc.w, c1.w);
    }
    return ((c0.x + c0.y) + (c0.z + c0.w)) + ((c1.x + c1.y) + (c1.z + c1.w));
}

// ---------------------------------------------------------------------------
template <int NS>
__device__ __forceinline__ void attn_body(const float* __restrict__ K,
                                          const float* __restrict__ Q,
                                          int a, int tid,
                                          float* __restrict__ ka,
                                          float* __restrict__ sp,
                                          float* __restrict__ smv,
                                          float* __restrict__ p) {
    float k0 = 0.f, k1 = 0.f;
#pragma unroll
    for (int n = 0; n < NS; ++n) {
        k0 += K[(size_t)n * PHS + (size_t)a * H + tid];
        k1 += K[(size_t)n * PHS + (size_t)a * H + tid + 256];
    }
    ka[tid] = k0; ka[tid + 256] = k1;
    __syncthreads();

    {
        int b = tid & 63;
        int t = tid >> 6;
        sp[t * 65 + b] = score_part<NS>(Q, ka, b, t);
        if (tid < 4) sp[tid * 65 + 64] = score_part<NS>(Q, ka, 64, tid);
    }
    __syncthreads();

    if (tid < S) {
        smv[tid] = (sp[tid] + sp[65 + tid]) + (sp[130 + tid] + sp[195 + tid]);
    }
    __syncthreads();

    float maxv = -INFINITY;
    for (int i = 0; i < S; ++i) maxv = fmaxf(maxv, smv[i]);
    float sum = 0.0f;
    for (int i = 0; i < S; ++i) sum += expf(smv[i] - maxv);
    float inv = 1.0f / sum;
    if (tid < S) p[tid] = expf(smv[tid] - maxv) * inv;
    __syncthreads();
}

// ---------------------------------------------------------------------------
// Layer-1 attention: one block per (a, slot), NS=2, writes att rows.
// ---------------------------------------------------------------------------
__global__ void __launch_bounds__(256, 1)
attn1_kernel(const float* __restrict__ kqvp,
             float* __restrict__ att) {
    int a = blockIdx.x;
    int slot = blockIdx.y;
    int tid = threadIdx.x;

    const float* base = kqvp + (size_t)slot * 6 * PHS;
    const float* K = base;
    const float* Q = base + 2 * (size_t)PHS;
    const float* V = base + 4 * (size_t)PHS;
    float* ao = att + (size_t)slot * PHS + (size_t)a * H;

    __shared__ float ka[H];
    __shared__ float sp[4 * 65];
    __shared__ float smv[S];
    __shared__ float p[S];

    attn_body<2>(K, Q, a, tid, ka, sp, smv, p);

#pragma unroll
    for (int rep = 0; rep < 2; ++rep) {
        int hh = tid + rep * 256;
        float a0 = 0.f, a1 = 0.f;
#pragma unroll 4
        for (int b = 0; b < 64; b += 2) {
            float v0 = V[(size_t)(b    ) * H + hh] + V[PHS + (size_t)(b    ) * H + hh];
            float v1 = V[(size_t)(b + 1) * H + hh] + V[PHS + (size_t)(b + 1) * H + hh];
            a0 = fmaf(p[b    ], v0, a0);
            a1 = fmaf(p[b + 1], v1, a1);
        }
        a0 = fmaf(p[64], V[(size_t)64 * H + hh] + V[PHS + (size_t)64 * H + hh], a0);
        ao[hh] = a0 + a1;
    }
}

// ---------------------------------------------------------------------------
// 4-row linear block with atomicAdd output (accumulator pattern).
// ---------------------------------------------------------------------------
__device__ __forceinline__ void lin4row_atomic_dev(const float* __restrict__ att,
                                                   int col0,
                                                   const float* __restrict__ L,
                                                   float* __restrict__ dst,
                                                   int s0, int tid) {
    __shared__ float Ar[4 * 256];
    __shared__ float4 red[4 * 128];

    {
        int rr = tid >> 6;
        int cc = tid & 63;
        *(float4*)(&Ar[rr * 256 + cc * 4]) =
            *(const float4*)(att + (size_t)(s0 + rr) * H + col0 + cc * 4);
    }
    __syncthreads();

    int h4 = (tid & 127) * 4;
    int jh = tid >> 7;
    const float* Lj = L + (size_t)(jh * 128) * H + h4;
    const float* A0 = Ar + jh * 128;

    float4 c0 = {0,0,0,0}, c1 = {0,0,0,0}, c2 = {0,0,0,0}, c3 = {0,0,0,0};
#pragma unroll 8
    for (int j = 0; j < 128; ++j) {
        float4 L4 = *(const float4*)(Lj + (size_t)j * H);
        float a0 = A0[j], a1 = A0[256 + j], a2 = A0[512 + j], a3 = A0[768 + j];
        c0.x = fmaf(a0, L4.x, c0.x); c0.y = fmaf(a0, L4.y, c0.y);
        c0.z = fmaf(a0, L4.z, c0.z); c0.w = fmaf(a0, L4.w, c0.w);
        c1.x = fmaf(a1, L4.x, c1.x); c1.y = fmaf(a1, L4.y, c1.y);
        c1.z = fmaf(a1, L4.z, c1.z); c1.w = fmaf(a1, L4.w, c1.w);
        c2.x = fmaf(a2, L4.x, c2.x); c2.y = fmaf(a2, L4.y, c2.y);
        c2.z = fmaf(a2, L4.z, c2.z); c2.w = fmaf(a2, L4.w, c2.w);
        c3.x = fmaf(a3, L4.x, c3.x); c3.y = fmaf(a3, L4.y, c3.y);
        c3.z = fmaf(a3, L4.z, c3.z); c3.w = fmaf(a3, L4.w, c3.w);
    }

    if (jh == 1) {
        int x = tid & 127;
        red[x] = c0; red[128 + x] = c1; red[256 + x] = c2; red[384 + x] = c3;
    }
    __syncthreads();
    if (jh == 0) {
        float4 r0 = red[tid], r1 = red[128 + tid], r2 = red[256 + tid], r3 = red[384 + tid];
        c0.x += r0.x; c0.y += r0.y; c0.z += r0.z; c0.w += r0.w;
        c1.x += r1.x; c1.y += r1.y; c1.z += r1.z; c1.w += r1.w;
        c2.x += r2.x; c2.y += r2.y; c2.z += r2.z; c2.w += r2.w;
        c3.x += r3.x; c3.y += r3.y; c3.z += r3.z; c3.w += r3.w;
        float* d0 = dst + (size_t)(s0 + 0) * H + h4;
        float* d1 = dst + (size_t)(s0 + 1) * H + h4;
        float* d2 = dst + (size_t)(s0 + 2) * H + h4;
        float* d3 = dst + (size_t)(s0 + 3) * H + h4;
        atomicAdd(d0 + 0, c0.x); atomicAdd(d0 + 1, c0.y);
        atomicAdd(d0 + 2, c0.z); atomicAdd(d0 + 3, c0.w);
        atomicAdd(d1 + 0, c1.x); atomicAdd(d1 + 1, c1.y);
        atomicAdd(d1 + 2, c1.z); atomicAdd(d1 + 3, c1.w);
        atomicAdd(d2 + 0, c2.x); atomicAdd(d2 + 1, c2.y);
        atomicAdd(d2 + 2, c2.z); atomicAdd(d2 + 3, c2.w);
        atomicAdd(d3 + 0, c3.x); atomicAdd(d3 + 1, c3.y);
        atomicAdd(d3 + 2, c3.z); atomicAdd(d3 + 3, c3.w);
    }
}

// ---------------------------------------------------------------------------
// Mega linear: lin1 6 segs -> y2acc, lin2 segs 0..3 -> pacc2 (atomic),
// lin3 row-64 K-slices 0..15 -> tacc (atomic). Grid 234.
// ---------------------------------------------------------------------------
__global__ void __launch_bounds__(256, 1)
mega_lin_kernel(const float* __restrict__ att1,
                const float* __restrict__ lin1,
                const float* __restrict__ lin2,
                const float* __restrict__ lin3,
                float* __restrict__ y2acc,
                float* __restrict__ pacc2,
                float* __restrict__ tacc) {
    int bx = blockIdx.x;
    int tid = threadIdx.x;

    if (bx < 170) {
        int seg = bx / 17;      // 0..9
        int pnum = bx % 17;
        const float* att;
        const float* L;
        float* dst;
        if (seg < 6) {
            att = att1 + (size_t)(seg >> 1) * PHS;
            L   = lin1 + (size_t)(seg * 256) * H;
            dst = y2acc;
        } else {
            int s2 = seg - 6;
            att = att1 + (size_t)(s2 >> 1) * PHS;
            L   = lin2 + (size_t)(s2 * 256) * H;
            dst = pacc2;
        }
        lin4row_atomic_dev(att, (seg & 1) * 256, L, dst, pnum * 4, tid);
    } else {
        int idx = bx - 170;                   // 0..63
        int j2 = (idx & 3) * 256 + tid;
        int ks = idx >> 2;                    // 0..15
        const float* row = att1 + (size_t)(ks >> 3) * PHS + (size_t)64 * H;
        int j0 = (ks & 7) * 64;
        int jbase = ks * 64;
        float a0 = 0.f, a1 = 0.f, a2 = 0.f, a3 = 0.f;
        for (int j = 0; j < 64; j += 4) {
            a0 = fmaf(row[j0 + j + 0], lin3[(size_t)(jbase + j + 0) * 1024 + j2], a0);
            a1 = fmaf(row[j0 + j + 1], lin3[(size_t)(jbase + j + 1) * 1024 + j2], a1);
            a2 = fmaf(row[j0 + j + 2], lin3[(size_t)(jbase + j + 2) * 1024 + j2], a2);
            a3 = fmaf(row[j0 + j + 3], lin3[(size_t)(jbase + j + 3) * 1024 + j2], a3);
        }
        atomicAdd(&tacc[j2], (a0 + a1) + (a2 + a3));
    }
}

// ---------------------------------------------------------------------------
// Fused layer-2 attention + lin2 segs 4,5 + pacc2 + relu -> y3 row a.
// 65 blocks, 256 thr, NS=4 kqvp layout (slot 0).
// ---------------------------------------------------------------------------
__global__ void __launch_bounds__(256, 1)
attn2_lin2_kernel(const float* __restrict__ kqvp,
                  const float* __restrict__ lin2,
                  const float* __restrict__ pacc2,
                  float* __restrict__ y3) {
    int a = blockIdx.x;
    int tid = threadIdx.x;

    const float* K = kqvp;
    const float* Q = kqvp + 4 * (size_t)PHS;
    const float* V = kqvp + 8 * (size_t)PHS;

    __shared__ float ka[H];
    __shared__ float sp[4 * 65];
    __shared__ float smv[S];
    __shared__ float p[S];
    __shared__ float arow[H];
    __shared__ float4 red[128];

    attn_body<4>(K, Q, a, tid, ka, sp, smv, p);

#pragma unroll
    for (int rep = 0; rep < 2; ++rep) {
        int hh = tid + rep * 256;
        float a0 = 0.f, a1 = 0.f;
#pragma unroll 4
        for (int b = 0; b < 64; b += 2) {
            float v0 = 0.f, v1 = 0.f;
#pragma unroll
            for (int n = 0; n < 4; ++n) {
                v0 += V[(size_t)n * PHS + (size_t)(b    ) * H + hh];
                v1 += V[(size_t)n * PHS + (size_t)(b + 1) * H + hh];
            }
            a0 = fmaf(p[b    ], v0, a0);
            a1 = fmaf(p[b + 1], v1, a1);
        }
        {
            float v0 = 0.f;
#pragma unroll
            for (int n = 0; n < 4; ++n) v0 += V[(size_t)n * PHS + (size_t)64 * H + hh];
            a0 = fmaf(p[64], v0, a0);
        }
        arow[hh] = a0 + a1;
    }
    __syncthreads();

    // lin2 rows 1024..1535: out[a][h] = sum_j arow[j]*lin2[(1024+j)*H+h]
    int h4 = (tid & 127) * 4;
    int jh = tid >> 7;
    const float* Lj = lin2 + (size_t)(1024 + jh * 256) * H + h4;
    const float* A0 = arow + jh * 256;

    float4 c = {0,0,0,0};
#pragma unroll 8
    for (int j = 0; j < 256; ++j) {
        float4 L4 = *(const float4*)(Lj + (size_t)j * H);
        float av = A0[j];
        c.x = fmaf(av, L4.x, c.x);
        c.y = fmaf(av, L4.y, c.y);
        c.z = fmaf(av, L4.z, c.z);
        c.w = fmaf(av, L4.w, c.w);
    }
    if (jh == 1) red[tid & 127] = c;
    __syncthreads();
    if (jh == 0) {
        float4 r = red[tid];
        float4 pa = *(const float4*)(pacc2 + (size_t)a * H + h4);
        c.x = fmaxf(c.x + r.x + pa.x, 0.f);
        c.y = fmaxf(c.y + r.y + pa.y, 0.f);
        c.z = fmaxf(c.z + r.z + pa.z, 0.f);
        c.w = fmaxf(c.w + r.w + pa.w, 0.f);
        *(float4*)(y3 + (size_t)a * H + h4) = c;
    }
}

// ---------------------------------------------------------------------------
// Layer-3 attention (row 64 only, NS=4) + lin3 slices 16..23 -> tacc (atomic).
// grid (4,8).
// ---------------------------------------------------------------------------
__global__ void __launch_bounds__(256, 1)
attn3_lin3c_kernel(const float* __restrict__ kqvp,
                   const float* __restrict__ lin3,
                   float* __restrict__ tacc) {
    int tid = threadIdx.x;
    int ks  = 16 + blockIdx.y;
    int j2  = blockIdx.x * 256 + tid;
    int j0  = (ks & 7) * 64;

    const float* K = kqvp;
    const float* Q = kqvp + 4 * (size_t)PHS;
    const float* V = kqvp + 8 * (size_t)PHS;

    __shared__ float ka[H];
    __shared__ float sp[4 * 65];
    __shared__ float smv[S];
    __shared__ float p[S];
    __shared__ float att_s[64];

    attn_body<4>(K, Q, 64, tid, ka, sp, smv, p);

    if (tid < 64) {
        int hh = j0 + tid;
        float a0 = 0.f, a1 = 0.f;
#pragma unroll 4
        for (int b = 0; b < 64; b += 2) {
            float v0 = 0.f, v1 = 0.f;
#pragma unroll
            for (int n = 0; n < 4; ++n) {
                v0 += V[(size_t)n * PHS + (size_t)(b    ) * H + hh];
                v1 += V[(size_t)n * PHS + (size_t)(b + 1) * H + hh];
            }
            a0 = fmaf(p[b    ], v0, a0);
            a1 = fmaf(p[b + 1], v1, a1);
        }
        {
            float v0 = 0.f;
#pragma unroll
            for (int n = 0; n < 4; ++n) v0 += V[(size_t)n * PHS + (size_t)64 * H + hh];
            a0 = fmaf(p[64], v0, a0);
        }
        att_s[tid] = a0 + a1;
    }
    __syncthreads();

    int jbase = ks * 64;
    float a0 = 0.f, a1 = 0.f, a2 = 0.f, a3 = 0.f;
    for (int j = 0; j < 64; j += 4) {
        a0 = fmaf(att_s[j + 0], lin3[(size_t)(jbase + j + 0) * 1024 + j2], a0);
        a1 = fmaf(att_s[j + 1], lin3[(size_t)(jbase + j + 1) * 1024 + j2], a1);
        a2 = fmaf(att_s[j + 2], lin3[(size_t)(jbase + j + 2) * 1024 + j2], a2);
        a3 = fmaf(att_s[j + 3], lin3[(size_t)(jbase + j + 3) * 1024 + j2], a3);
    }
    atomicAdd(&tacc[j2], (a0 + a1) + (a2 + a3));
}

// ---------------------------------------------------------------------------
// lin4: t = relu(tacc); partial dot -> uacc (atomic). grid (2,16).
// ---------------------------------------------------------------------------
__global__ void lin4_kernel(const float* __restrict__ tacc,
                            const float* __restrict__ lin4,
                            float* __restrict__ uacc) {
    __shared__ float tl[64];
    int hh = blockIdx.x * 256 + threadIdx.x;
    int ks = blockIdx.y;
    int j2base = ks * 64;

    if (threadIdx.x < 64) {
        tl[threadIdx.x] = fmaxf(tacc[j2base + threadIdx.x], 0.f);
    }
    __syncthreads();

    float a0 = 0.f, a1 = 0.f, a2 = 0.f, a3 = 0.f;
    for (int j = 0; j < 64; j += 4) {
        a0 = fmaf(tl[j + 0], lin4[(size_t)(j2base + j + 0) * H + hh], a0);
        a1 = fmaf(tl[j + 1], lin4[(size_t)(j2base + j + 1) * H + hh], a1);
        a2 = fmaf(tl[j + 2], lin4[(size_t)(j2base + j + 2) * H + hh], a2);
        a3 = fmaf(tl[j + 3], lin4[(size_t)(j2base + j + 3) * H + hh], a3);
    }
    atomicAdd(&uacc[hh], (a0 + a1) + (a2 + a3));
}

__global__ void final_out_kernel(const float* __restrict__ uacc,
                                 const float* __restrict__ lin5,
                                 float* __restrict__ out) {
    __shared__ float u[H];
    __shared__ float pr[8][64];
    int tid = threadIdx.x;   // 512

    u[tid] = tanhf(uacc[tid]);
    __syncthreads();

    int o  = tid & 63;
    int sl = tid >> 6;
    float acc = 0.f;
    int h0 = sl * 64;
#pragma unroll 8
    for (int j = 0; j < 64; ++j) {
        acc = fmaf(u[h0 + j], lin5[(h0 + j) * 64 + o], acc);
    }
    pr[sl][o] = acc;
    __syncthreads();

    if (tid < 64) {
        float s = 0.f;
#pragma unroll
        for (int p = 0; p < 8; ++p) s += pr[p][tid];
        out[tid] = s;
    }
}

// ---------------------------------------------------------------------------
extern "C" void kernel_launch(void* const* d_in, const int* in_sizes, int n_in,
                              void* d_out, int out_size, void* d_ws, size_t ws_size,
                              hipStream_t stream) {
    const float* inputs  = (const float*)d_in[0];
    const float* emb     = (const float*)d_in[1];
    const float* wq      = (const float*)d_in[2];
    const float* wk      = (const float*)d_in[3];
    const float* wv      = (const float*)d_in[4];
    const float* linear1 = (const float*)d_in[5];
    const float* linear2 = (const float*)d_in[6];
    const float* linear3 = (const float*)d_in[7];
    const float* linear4 = (const float*)d_in[8];
    const float* linear5 = (const float*)d_in[9];
    float* out = (float*)d_out;

    float* ws    = (float*)d_ws;
    float* y1    = ws;                  // PHS
    float* kqvp  = y1    + PHS;         // 18*PHS max
    float* att1  = kqvp  + 18 * PHS;    // 3*PHS
    float* y2acc = att1  + 3 * PHS;     // PHS
    float* pacc2 = y2acc + PHS;         // PHS
    float* y3    = pacc2 + PHS;         // PHS
    float* tacc  = y3    + PHS;         // 1024
    float* uacc  = tacc  + 1024;        // 512

    const int nbp = PHS / 256;          // 160

    scale_embed_zero_kernel<<<nbp, 256, 0, stream>>>(inputs, emb, y1,
                                                     y2acc, pacc2, tacc, uacc);

    // ---- Layer 1 (KSPLIT=2: 288 blocks) ----
    kqv_gemm_tiled<2, 0><<<dim3(32, 3, 3), 256, 0, stream>>>(wq, wk, wv, 0, y1, kqvp);
    attn1_kernel<<<dim3(S, 3), 256, 0, stream>>>(kqvp, att1);
    mega_lin_kernel<<<234, 256, 0, stream>>>(att1, linear1, linear2, linear3,
                                             y2acc, pacc2, tacc);

    // ---- Layer 2 (head 2; KSPLIT=4: 192 blocks; relu inline on y2acc) ----
    kqv_gemm_tiled<4, 1><<<dim3(64, 3, 1), 256, 0, stream>>>(wq, wk, wv, 5, y2acc, kqvp);
    attn2_lin2_kernel<<<S, 256, 0, stream>>>(kqvp, linear2, pacc2, y3);

    // ---- Layer 3 (head 2; KSPLIT=4) ----
    kqv_gemm_tiled<4, 0><<<dim3(64, 3, 1), 256, 0, stream>>>(wq, wk, wv, 8, y3, kqvp);
    attn3_lin3c_kernel<<<dim3(4, 8), 256, 0, stream>>>(kqvp, linear3, tacc);

    // ---- Final ----
    lin4_kernel<<<dim3(2, 16), 256, 0, stream>>>(tacc, linear4, uacc);
    final_out_kernel<<<1, 512, 0, stream>>>(uacc, linear5, out);
}